// Round 8
// baseline (8788.817 us; speedup 1.0000x reference)
//
#include <hip/hip_runtime.h>

typedef short bf16x8 __attribute__((ext_vector_type(8)));
typedef float f32x4 __attribute__((ext_vector_type(4)));
typedef unsigned short u16;
typedef unsigned int u32;
typedef unsigned long long u64;

static constexpr int B = 2048, S = 128, D = 128, H = 256;
static constexpr size_t PH = (size_t)B * H;

// LDS (u16 units): W resident [16 ktiles][128 zrows][32 k] = 64K u16 (128KB)
//                  Wp resident [8 ktiles][16 rows][32 k]   = 4K u16  (8KB)
#define L_WP   65536
#define L_TOT  69632      // 139264 bytes

__device__ __forceinline__ u16 f2bf(float x){ u32 u=__float_as_uint(x); return (u16)((u + 0x7fffu + ((u>>16)&1u))>>16); }
__device__ __forceinline__ float bf2f(u16 h){ return __uint_as_float(((u32)h)<<16); }
__device__ __forceinline__ float fsig(float x){ return 1.0f/(1.0f+__expf(-x)); }
__device__ __forceinline__ float ftanh(float x){ return 1.0f - 2.0f/(__expf(2.0f*x)+1.0f); }

__device__ __forceinline__ void gl_lds16(const void* g, const u16* l){
  __builtin_amdgcn_global_load_lds((const __attribute__((address_space(1))) void*)g,
      (__attribute__((address_space(3))) void*)l, 16, 0, 0);
}
__device__ __forceinline__ u64 ald64(const u32* p){
  return __hip_atomic_load((const u64*)p, __ATOMIC_RELAXED, __HIP_MEMORY_SCOPE_AGENT);
}
__device__ __forceinline__ u32 ald32(const u32* p){
  return __hip_atomic_load(p, __ATOMIC_RELAXED, __HIP_MEMORY_SCOPE_AGENT);
}
__device__ __forceinline__ void ast32(u32* p, u32 v){
  __hip_atomic_store(p, v, __ATOMIC_RELAXED, __HIP_MEMORY_SCOPE_AGENT);
}

__global__ __launch_bounds__(256) void cvtk(const float* __restrict__ s, u16* __restrict__ d, int n){
  int i = (blockIdx.x*256 + threadIdx.x)*4;
  if (i+3 < n){
    float4 v = *(const float4*)(s+i);
    d[i]=f2bf(v.x); d[i+1]=f2bf(v.y); d[i+2]=f2bf(v.z); d[i+3]=f2bf(v.w);
  }
}
__global__ __launch_bounds__(256) void addk(const float* __restrict__ a, const float* __restrict__ b,
                                            float* __restrict__ o, int n){
  int i = blockIdx.x*256 + threadIdx.x; if (i<n) o[i]=a[i]+b[i];
}

// One phase job. K is split into nt tiles of 32; tiles < n1 come from input-1.
struct Ph {
  const float* xf; int t;          // fp32 x source for tiles<n1 (enc L0) or null
  const u32 *A1, *A2;              // packed hi|lo u32 planes
  int n1, nt;
  size_t gb;                       // batch-row base (block covers 64*MF rows)
  const float* bs;                 // fused bias (4H fp32)
  u32* outP;                       // h output plane (packed hi|lo)
  int doprj; const float* bout; float* out; int tau;
};

// stage a W-slice into resident LDS: [ktile][128 zrows][32 k], linear (no swizzle).
// zrow zr: gate = zr>>5, col j = nn*32 + (zr&31); one gl_lds16 per thread per ktile.
__device__ __forceinline__ void stage_w(u16* lds, int nn, const int tid,
                                        const u16* W1, int ldw1, int t1,
                                        const u16* W2, int ldw2, int t2){
  const int rl = tid >> 2, sl = tid & 3;
  const size_t grow = (size_t)((rl >> 5) * H + nn * 32 + (rl & 31));
  for (int kt = 0; kt < t1 + t2; ++kt){
    const u16* src;
    if (kt < t1) src = W1 + grow * ldw1 + kt * 32 + sl * 8;
    else         src = W2 + grow * ldw2 + (kt - t1) * 32 + sl * 8;
    gl_lds16(src, &lds[kt * 4096 + (tid >> 6) * 512]);
  }
}

__device__ __forceinline__ void unpack_plane(const u64 (&ra)[4], bf16x8& ah, bf16x8& al){
  u32 dh[4], dl[4];
  #pragma unroll
  for (int i = 0; i < 4; ++i){
    const u32 e0 = (u32)ra[i], e1 = (u32)(ra[i] >> 32);
    dh[i] = (e0 >> 16) | (e1 & 0xffff0000u);
    dl[i] = (e0 & 0xffffu) | (e1 << 16);
  }
  ah = *(bf16x8*)dh; al = *(bf16x8*)dl;
}
__device__ __forceinline__ void unpack_f32(const u64 (&ra)[4], bf16x8& ah, bf16x8& al){
  u32 dh[4], dl[4];
  #pragma unroll
  for (int i = 0; i < 4; ++i){
    const float f0 = __uint_as_float((u32)ra[i]);
    const float f1 = __uint_as_float((u32)(ra[i] >> 32));
    const u16 h0 = f2bf(f0), h1 = f2bf(f1);
    const u16 l0 = f2bf(f0 - bf2f(h0)), l1 = f2bf(f1 - bf2f(h1));
    dh[i] = (u32)h0 | ((u32)h1 << 16);
    dl[i] = (u32)l0 | ((u32)l1 << 16);
  }
  ah = *(bf16x8*)dh; al = *(bf16x8*)dl;
}

// 8 waves = 4 m-groups x 2 n-halves. MF=2: 128 rows; MF=1: 64 rows. 128 z-cols.
// No LDS staging, no intra-phase barriers: A prefetched to regs, W LDS-resident.
template<int MF>
__device__ __forceinline__ void run_layer(u16* lds, const Ph& J,
    const int tid, const int w, const int lr, const int lc, const int nn,
    float (&cst)[MF][4])
{
  const int nh = w & 1, mg = w >> 1;
  const int nt = J.nt, n1 = J.n1;
  const int kc = lc * 8;

  int woff[4];
  #pragma unroll
  for (int q = 0; q < 4; ++q) woff[q] = (q*32 + nh*16 + lr)*32 + kc;
  const int poff = lr*32 + kc;

  size_t arow[MF];
  #pragma unroll
  for (int mf = 0; mf < MF; ++mf)
    arow[mf] = (J.gb + (size_t)mg*(16*MF) + mf*16 + lr) * H;

  f32x4 acc[MF][4];
  f32x4 accp[MF];
  #pragma unroll
  for (int mf=0; mf<MF; ++mf){
    accp[mf] = (f32x4){0.f,0.f,0.f,0.f};
    #pragma unroll
    for (int q=0; q<4; ++q) acc[mf][q] = (f32x4){0.f,0.f,0.f,0.f};
  }

  u64 a0[MF][4], a1[MF][4];

  auto loadA = [&](int tile, u64 (&ra)[MF][4]){
    if (J.xf && tile < n1){
      #pragma unroll
      for (int mf = 0; mf < MF; ++mf){
        const float* s = J.xf +
            ((J.gb + (size_t)mg*(16*MF) + mf*16 + lr)*S + J.t)*D + tile*32 + kc;
        #pragma unroll
        for (int i = 0; i < 4; ++i) ra[mf][i] = *(const u64*)(s + 2*i);
      }
    } else {
      const u32* pl; int k0;
      if (tile < n1){ pl = J.A1; k0 = tile*32; }
      else          { pl = J.A2; k0 = (tile - n1)*32; }
      #pragma unroll
      for (int mf = 0; mf < MF; ++mf){
        const u32* s = pl + arow[mf] + k0 + kc;
        #pragma unroll
        for (int i = 0; i < 4; ++i) ra[mf][i] = ald64(s + 2*i);
      }
    }
  };

  auto comp = [&](int tile, u64 (&ra)[MF][4]){
    bf16x8 ah[MF], al[MF];
    const bool xp = (J.xf != nullptr) && (tile < n1);
    #pragma unroll
    for (int mf = 0; mf < MF; ++mf){
      if (xp) unpack_f32(ra[mf], ah[mf], al[mf]);
      else    unpack_plane(ra[mf], ah[mf], al[mf]);
    }
    #pragma unroll
    for (int q = 0; q < 4; ++q){
      bf16x8 wq = *(const bf16x8*)&lds[tile*4096 + woff[q]];
      #pragma unroll
      for (int mf = 0; mf < MF; ++mf){
        acc[mf][q] = __builtin_amdgcn_mfma_f32_16x16x32_bf16(ah[mf], wq, acc[mf][q], 0,0,0);
        acc[mf][q] = __builtin_amdgcn_mfma_f32_16x16x32_bf16(al[mf], wq, acc[mf][q], 0,0,0);
      }
    }
    if (J.doprj && nh == 0 && tile < 8){
      bf16x8 wp = *(const bf16x8*)&lds[L_WP + tile*512 + poff];
      #pragma unroll
      for (int mf = 0; mf < MF; ++mf){
        accp[mf] = __builtin_amdgcn_mfma_f32_16x16x32_bf16(ah[mf], wp, accp[mf], 0,0,0);
        accp[mf] = __builtin_amdgcn_mfma_f32_16x16x32_bf16(al[mf], wp, accp[mf], 0,0,0);
      }
    }
  };

  // 2-step software pipeline, static buffer names (nt is always even)
  loadA(0, a0);
  for (int t = 0; t < nt; t += 2){
    if (t + 1 < nt) loadA(t + 1, a1);
    comp(t, a0);
    if (t + 2 < nt) loadA(t + 2, a0);
    comp(t + 1, a1);
  }

  // epilogue: gates -> c,h ; packed coherent h store
  {
    const int j = nn*32 + nh*16 + lr;
    const float b0 = J.bs[j], b1 = J.bs[H+j], b2 = J.bs[2*H+j], b3 = J.bs[3*H+j];
    #pragma unroll
    for (int mf = 0; mf < MF; ++mf){
      #pragma unroll
      for (int r = 0; r < 4; ++r){
        const size_t m = J.gb + (size_t)mg*(16*MF) + mf*16 + lc*4 + r;
        const float ig = fsig (acc[mf][0][r] + b0);
        const float fg = fsig (acc[mf][1][r] + b1);
        const float gg = ftanh(acc[mf][2][r] + b2);
        const float og = fsig (acc[mf][3][r] + b3);
        const float c  = fg*cst[mf][r] + ig*gg;
        cst[mf][r] = c;
        const float h = og * ftanh(c);
        const u16 hb = f2bf(h);
        const u16 lb = f2bf(h - bf2f(hb));
        ast32(J.outP + m*H + j, ((u32)hb << 16) | lb);
      }
    }
    if (J.doprj && nh == 0){
      const int col = nn*16 + lr;
      const float bo = J.bout[col];
      #pragma unroll
      for (int mf = 0; mf < MF; ++mf){
        #pragma unroll
        for (int r = 0; r < 4; ++r){
          const size_t m = J.gb + (size_t)mg*(16*MF) + mf*16 + lc*4 + r;
          J.out[(m*S + J.tau)*D + col] = accp[mf][r] + bo;
        }
      }
    }
  }
}

struct GG {
  const float* x;
  const u16* W[9];
  const float* bs; const float* bout;
  u32* P;           // 9 packed planes of B*H u32 (8 live + 1 sink)
  float* out; u32* flags;
};

// planes: 0,1: eh1  2,3: eh2  4,5: dh1  6,7: dh2  8: sink   (h(t) -> parity (t+1)&1)
__global__ __launch_bounds__(512, 1) void persist(GG g)
{
  __shared__ u16 lds[L_TOT];
  const int tid = threadIdx.x, w = tid>>6, l = tid&63, lr = l&15, lc = l>>4;
  const int bid = blockIdx.x;
  // round-6 decode: slice co-located on one XCD (bid%8 == slice%8)
  const int slice = bid & 15, idx = bid >> 4, role = idx >> 3, nn = idx & 7;
  const size_t gb0 = (size_t)slice * 128;
  u32* flg = g.flags + slice*16;
  auto P = [&](int i){ return g.P + (size_t)i * PH; };

  // initial resident W: role0 = enc L0 (12 ktiles), role1 = enc L1 (16 ktiles)
  if (role == 0) stage_w(lds, nn, tid, g.W[0], D, 4, g.W[1], H, 8);
  else           stage_w(lds, nn, tid, g.W[2], H, 8, g.W[3], H, 8);
  // proj weights resident (role0 uses them in dec): [8 kt][16 rows][32 k]
  if (role == 0){
    const int kt = tid >> 6, zr = (tid >> 2) & 15, sl = tid & 3;
    gl_lds16(g.W[8] + (size_t)(nn*16 + zr)*H + kt*32 + sl*8,
             &lds[L_WP + (tid >> 6) * 512]);
  }
  asm volatile("s_waitcnt vmcnt(0)" ::: "memory");
  __syncthreads();

  float cE[2][4]  = {{0,0,0,0},{0,0,0,0}};
  float cD0[1][4] = {{0,0,0,0}};
  float cD1[1][4] = {{0,0,0,0}};

  for (int p = 0; p < 388; ++p){
    if (role == 0){
      if (p < 128){
        const int t = p, pr = t&1, pw = (t+1)&1;
        Ph J{g.x, t, nullptr, P(0+pr), 4, 12,
             gb0, g.bs, P(0+pw), 0, nullptr, nullptr, 0};
        run_layer<2>(lds, J, tid, w, lr, lc, nn, cE);
      } else if (p == 128){
        // enc done for role0 -> load decoder L0 weights (idle phase otherwise)
        stage_w(lds, nn, tid, g.W[4], H, 8, g.W[5], H, 8);
        asm volatile("s_waitcnt vmcnt(0)" ::: "memory");
        __syncthreads();
      } else if (p >= 129 && p <= 384){
        const int q = p-129, t = q>>1, h = q&1, pr = t&1, pw = (t+1)&1;
        const u32* a1 = (t == 0) ? P(2) : P(6+pr);
        Ph J{nullptr, 0, a1, P(4+pr), 8, 16,
             gb0 + (size_t)h*64, g.bs + 2048, P(4+pw),
             (t >= 1) ? 1 : 0, g.bout, g.out, t-1};
        if (h == 0) run_layer<1>(lds, J, tid, w, lr, lc, nn, cD0);
        else        run_layer<1>(lds, J, tid, w, lr, lc, nn, cD1);
      } else if (p >= 386){
        // tail proj(tau=127) for half h: junk LSTM into sink plane
        const int h = p - 386;
        Ph J{nullptr, 0, P(6), P(4), 8, 16,
             gb0 + (size_t)h*64, g.bs + 2048, P(8), 1, g.bout, g.out, 127};
        float cj[1][4] = {{0,0,0,0}};
        run_layer<1>(lds, J, tid, w, lr, lc, nn, cj);
      }
      // p==385 idle
    } else {
      if (p >= 1 && p <= 128){
        const int t = p-1, pr = t&1, pw = (t+1)&1;
        Ph J{nullptr, 0, P(0+pw), P(2+pr), 8, 16,
             gb0, g.bs + 1024, P(2+pw), 0, nullptr, nullptr, 0};
        run_layer<2>(lds, J, tid, w, lr, lc, nn, cE);
      } else if (p == 129){
        // load decoder L1 weights (idle phase otherwise)
        stage_w(lds, nn, tid, g.W[6], H, 8, g.W[7], H, 8);
        asm volatile("s_waitcnt vmcnt(0)" ::: "memory");
        __syncthreads();
      } else if (p >= 130 && p <= 385){
        const int r2 = p-130, t = r2>>1, h = r2&1, pr = t&1, pw = (t+1)&1;
        Ph J{nullptr, 0, P(4+pw), P(6+pr), 8, 16,
             gb0 + (size_t)h*64, g.bs + 3072, P(6+pw), 0, nullptr, nullptr, 0};
        if (h == 0) run_layer<1>(lds, J, tid, w, lr, lc, nn, cD0);
        else        run_layer<1>(lds, J, tid, w, lr, lc, nn, cD1);
      }
    }
    // slice barrier: store-only arrival + parallel flag poll (no RMW, no fences)
    asm volatile("s_waitcnt vmcnt(0)" ::: "memory");
    __syncthreads();
    if (tid == 0) ast32(&flg[idx], (u32)(p + 1));
    if (tid < 16){
      while (ald32(&flg[tid]) < (u32)(p + 1))
        __builtin_amdgcn_s_sleep(1);
    }
    __syncthreads();
  }
}

extern "C" void kernel_launch(void* const* d_in, const int* in_sizes, int n_in,
                              void* d_out, int out_size, void* d_ws, size_t ws_size,
                              hipStream_t stream)
{
  const float* x     = (const float*)d_in[0];
  const float* eWih0 = (const float*)d_in[1];
  const float* eWhh0 = (const float*)d_in[2];
  const float* ebih0 = (const float*)d_in[3];
  const float* ebhh0 = (const float*)d_in[4];
  const float* eWih1 = (const float*)d_in[5];
  const float* eWhh1 = (const float*)d_in[6];
  const float* ebih1 = (const float*)d_in[7];
  const float* ebhh1 = (const float*)d_in[8];
  const float* dWih0 = (const float*)d_in[9];
  const float* dWhh0 = (const float*)d_in[10];
  const float* dbih0 = (const float*)d_in[11];
  const float* dbhh0 = (const float*)d_in[12];
  const float* dWih1 = (const float*)d_in[13];
  const float* dWhh1 = (const float*)d_in[14];
  const float* dbih1 = (const float*)d_in[15];
  const float* dbhh1 = (const float*)d_in[16];
  const float* Wout  = (const float*)d_in[17];
  const float* bout  = (const float*)d_in[18];
  float* out = (float*)d_out;

  // ---- workspace layout ----
  u16* wc = (u16*)d_ws;
  const int szW[9] = {4*H*D, 4*H*H, 4*H*H, 4*H*H, 4*H*H, 4*H*H, 4*H*H, 4*H*H, D*H};
  const float* srcW[9] = {eWih0,eWhh0,eWih1,eWhh1,dWih0,dWhh0,dWih1,dWhh1,Wout};
  u16* dstW[9]; size_t woff = 0;
  for (int i = 0; i < 9; ++i){ dstW[i] = wc + woff; woff += (size_t)szW[i]; }
  woff = (woff + 7) & ~(size_t)7;
  float* bs = (float*)(wc + woff);
  u32* pl    = (u32*)(bs + 4*1024);      // planes P0..P8 (9*PH u32), then flags
  u32* flags = pl + 9*PH;                // 16 slices x 16 u32

  for (int i = 0; i < 9; ++i)
    cvtk<<<dim3((szW[i]+1023)/1024), dim3(256), 0, stream>>>(srcW[i], dstW[i], szW[i]);
  addk<<<dim3(4), dim3(256), 0, stream>>>(ebih0, ebhh0, bs,        1024);
  addk<<<dim3(4), dim3(256), 0, stream>>>(ebih1, ebhh1, bs + 1024, 1024);
  addk<<<dim3(4), dim3(256), 0, stream>>>(dbih0, dbhh0, bs + 2048, 1024);
  addk<<<dim3(4), dim3(256), 0, stream>>>(dbih1, dbhh1, bs + 3072, 1024);
  // zero ALL planes AND flags every call (graph replays included)
  hipMemsetAsync(pl, 0, (9*PH + 1024) * sizeof(u32), stream);

  GG g;
  g.x = x;
  for (int i = 0; i < 9; ++i) g.W[i] = dstW[i];
  g.bs = bs; g.bout = bout;
  g.P = pl; g.out = out; g.flags = flags;

  persist<<<dim3(256), dim3(512), 0, stream>>>(g);
}